// Round 9
// baseline (261.304 us; speedup 1.0000x reference)
//
#include <hip/hip_runtime.h>
#include <hip/hip_bf16.h>

// ---------------------------------------------------------------------------
// CosineGraphAttentionLayer: O = softmax(beta*cos(xi,xj) + mask(adj)) @ xj
// N=M=8192, D=256, f32 in/out.
//
// R9 = R8 with the LDS-BW bottleneck split across ports: QK A-frags staged in
// LDS (depth-3 counted-vmcnt pipeline, 4 x 16KB buffers); PV B-frags read
// DIRECTLY from L2-resident xjF (1KB coalesced wave-loads, compiler-pipelined
// into the 8 independent PV acc chains). T5 setprio around MFMA clusters.
// Mask bitmask, pack formulas, epilogue, preps, reduce verbatim from R8.
// ---------------------------------------------------------------------------

typedef _Float16 half8  __attribute__((ext_vector_type(8)));
typedef _Float16 half4v __attribute__((ext_vector_type(4)));
typedef __fp16   fp16x2 __attribute__((ext_vector_type(2)));
typedef float    f32x16 __attribute__((ext_vector_type(16)));
typedef int      i32x4  __attribute__((ext_vector_type(4)));
typedef unsigned long long u64;

#define GAS __attribute__((address_space(1)))
#define LAS __attribute__((address_space(3)))

#define N_ROWS 8192
#define M_ROWS 8192
#define DDIM   256

// ---- prep: xi * beta/||xi|| -> f16 (validated) -----------------------------
__global__ void prep_scale(const float* __restrict__ x, _Float16* __restrict__ xs,
                           const float* __restrict__ betap) {
    int row  = blockIdx.x * 4 + (threadIdx.x >> 6);
    int lane = threadIdx.x & 63;
    const float4 v = *(const float4*)(x + (size_t)row * DDIM + lane * 4);
    float ss = v.x * v.x + v.y * v.y + v.z * v.z + v.w * v.w;
#pragma unroll
    for (int o = 32; o > 0; o >>= 1) ss += __shfl_xor(ss, o, 64);
    float sc = betap[0] / sqrtf(ss);
    half4v hv = {(_Float16)(v.x * sc), (_Float16)(v.y * sc),
                 (_Float16)(v.z * sc), (_Float16)(v.w * sc)};
    *(half4v*)(xs + (size_t)row * DDIM + lane * 4) = hv;
}

// ---- prep: xj -> frag-major xjA (normalized) / xjF (raw) (validated) -------
__global__ void prep_xj(const float* __restrict__ xj, half8* __restrict__ xjA,
                        half8* __restrict__ xjF) {
    __shared__ _Float16 tileR[32][272];
    __shared__ _Float16 tileN[32][272];
    __shared__ float red[32][8];
    __shared__ float rsc[32];
    const int t  = threadIdx.x;
    const int jb = blockIdx.x;
    const int row = t >> 3, seg = t & 7;
    const float* src = xj + (size_t)(jb * 32 + row) * DDIM + seg * 32;
    float4 v[8];
    float ss = 0.f;
#pragma unroll
    for (int q = 0; q < 8; ++q) {
        v[q] = ((const float4*)src)[q];
        ss += v[q].x * v[q].x + v[q].y * v[q].y + v[q].z * v[q].z + v[q].w * v[q].w;
    }
    red[row][seg] = ss;
    __syncthreads();
    if (t < 32) {
        float s = 0.f;
#pragma unroll
        for (int q = 0; q < 8; ++q) s += red[t][q];
        rsc[t] = 1.0f / sqrtf(s);
    }
    __syncthreads();
    const float sc = rsc[row];
#pragma unroll
    for (int q = 0; q < 8; ++q) {
        int c = seg * 32 + q * 4;
        tileR[row][c + 0] = (_Float16)v[q].x;
        tileR[row][c + 1] = (_Float16)v[q].y;
        tileR[row][c + 2] = (_Float16)v[q].z;
        tileR[row][c + 3] = (_Float16)v[q].w;
        tileN[row][c + 0] = (_Float16)(v[q].x * sc);
        tileN[row][c + 1] = (_Float16)(v[q].y * sc);
        tileN[row][c + 2] = (_Float16)(v[q].z * sc);
        tileN[row][c + 3] = (_Float16)(v[q].w * sc);
    }
    __syncthreads();
#pragma unroll
    for (int rep = 0; rep < 4; ++rep) {
        int idx = t + rep * 256;
        int kt = idx >> 6, l = idx & 63, il = l & 31, hh = l >> 5;
        half8 val = *(const half8*)&tileN[il][kt * 16 + hh * 8];
        xjA[((size_t)jb * 16 + kt) * 64 + l] = val;
    }
#pragma unroll
    for (int rep = 0; rep < 4; ++rep) {
        int idx = t + rep * 256;
        int f = idx >> 7, s = (idx >> 6) & 1, l = idx & 63, il = l & 31, hh = l >> 5;
        int d = f * 32 + il, jl = s * 16 + hh * 8;
        half8 val;
#pragma unroll
        for (int e = 0; e < 8; ++e) val[e] = tileR[jl + e][d];
        xjF[((size_t)jb * 16 + f * 2 + s) * 64 + l] = val;
    }
}

// ---- prep: adj -> ballot-packed bitmask (validated R6) ---------------------
// maskW[row*128 + jq*32 + k*4 + q] bit L = (adj[row][jq*2048 + k*256 + 4L + q] != 0)
__global__ void prep_mask(const int* __restrict__ adj, u64* __restrict__ maskW) {
    const int w    = threadIdx.x >> 6;
    const int lane = threadIdx.x & 63;
    const int task = blockIdx.x * 4 + w;
    const int row  = task >> 2;
    const int jq   = task & 3;
    const int* base = adj + (size_t)row * M_ROWS + jq * 2048 + lane * 4;
    i32x4 a[8];
#pragma unroll
    for (int k = 0; k < 8; ++k)
        a[k] = __builtin_nontemporal_load((const i32x4*)(base + k * 256));
    u64 myw = 0;
#pragma unroll
    for (int k = 0; k < 8; ++k) {
        u64 b0 = __ballot(a[k][0] != 0);
        u64 b1 = __ballot(a[k][1] != 0);
        u64 b2 = __ballot(a[k][2] != 0);
        u64 b3 = __ballot(a[k][3] != 0);
        if ((lane >> 2) == k) {
            int q = lane & 3;
            myw = (q == 0) ? b0 : (q == 1) ? b1 : (q == 2) ? b2 : b3;
        }
    }
    if (lane < 32)
        maskW[(size_t)row * 128 + jq * 32 + lane] = myw;
}

// ---- main fused kernel -----------------------------------------------------
// 256 blocks x 512 threads (1/CU). jsplit = bid&7 (1024-j eighth, == XCD id),
// itile = bid>>3 (256-i tile). Wave w owns i-subtile w (32 i), all 256 d.
// 32 iters of 32-j tiles. A-tile (16KB) staged via global_load_lds into 4
// rotating buffers, depth-3 (S(t+1),S(t+2) in flight; vmcnt(4) per iter).
// F-frags loaded directly from L2-resident xjF slice (no LDS).
__global__ __launch_bounds__(512, 2)
void attn_main(const _Float16* __restrict__ xi_s, const half8* __restrict__ xjA,
               const half8* __restrict__ xjF, const u64* __restrict__ maskW,
               float* __restrict__ part, float* __restrict__ denp) {
    extern __shared__ char lds[];
    const int tid  = threadIdx.x;
    const int w    = tid >> 6;
    const int lane = tid & 63;
    const int il   = lane & 31;
    const int h    = lane >> 5;

    const int bid    = blockIdx.x;
    const int jsplit = bid & 7;
    const int itile  = bid >> 3;
    const int ibase  = itile * 256;
    const int irow   = ibase + w * 32 + il;
    const int j0blk  = jsplit * 32;         // first 32-j block of our eighth

    half8 bq[16];
#pragma unroll
    for (int kt = 0; kt < 16; ++kt)
        bq[kt] = *(const half8*)(xi_s + (size_t)irow * DDIM + kt * 16 + h * 8);

    f32x16 acc[8];
#pragma unroll
    for (int f = 0; f < 8; ++f)
#pragma unroll
        for (int r = 0; r < 16; ++r) acc[f][r] = 0.f;
    float rden = 0.f;

    const u64* mrow = maskW + (size_t)irow * 128 + (jsplit >> 1) * 32;
    const int  kbase = (jsplit & 1) * 4;    // chunk base within quarter
    const char* gA = (const char*)xjA;
    const char* gF = (const char*)xjF;

    // STAGE A-tile T into buffer B: 16KB; each wave stages 2KB (2 x 1KB).
#define STAGE(T, B)                                                             \
    {                                                                           \
        const size_t blk = (size_t)(j0blk + (T)) * 16384;                       \
        const char* src = gA + blk + w * 2048 + (lane << 4);                    \
        char* dst = lds + (B) * 16384 + w * 2048 + (lane << 4);                 \
        __builtin_amdgcn_global_load_lds((const GAS unsigned int*)(src),        \
                                         (LAS unsigned int*)(dst), 16, 0, 0);   \
        __builtin_amdgcn_global_load_lds((const GAS unsigned int*)(src + 1024), \
                                         (LAS unsigned int*)(dst + 1024), 16, 0, 0); \
    }

    STAGE(0, 0);
    STAGE(1, 1);
    STAGE(2, 2);
    u64 cw0 = mrow[kbase * 4 + 0], cw1 = mrow[kbase * 4 + 1];
    u64 cw2 = mrow[kbase * 4 + 2], cw3 = mrow[kbase * 4 + 3];
    u64 nw0 = 0, nw1 = 0, nw2 = 0, nw3 = 0;

    for (int t = 0; t < 32; ++t) {
        // wait: tile t's 2 loads landed; S(t+1), S(t+2) may still fly
        if (t < 30) {
            asm volatile("s_waitcnt vmcnt(4)" ::: "memory");
        } else if (t == 30) {
            asm volatile("s_waitcnt vmcnt(2)" ::: "memory");
        } else {
            asm volatile("s_waitcnt vmcnt(0)" ::: "memory");
        }
        __builtin_amdgcn_s_barrier();
        __builtin_amdgcn_sched_barrier(0);

        // prefetch next mask group (every 8 tiles)
        if ((t & 7) == 0) {
            int k = kbase + (((t >> 3) + 1) & 3);
            nw0 = mrow[k * 4 + 0]; nw1 = mrow[k * 4 + 1];
            nw2 = mrow[k * 4 + 2]; nw3 = mrow[k * 4 + 3];
        }
        // stage 3 ahead into tile (t-1)'s buffer (all waves done with it)
        if (t < 29) STAGE(t + 3, (t + 3) & 3);

        const char* bufA = lds + (t & 3) * 16384;

        // QK^T: S^T[j][i], 32j x 32i — two interleaved chains for MFMA ILP
        f32x16 sacc0, sacc1;
#pragma unroll
        for (int r = 0; r < 16; ++r) { sacc0[r] = 0.f; sacc1[r] = 0.f; }
        __builtin_amdgcn_s_setprio(1);
#pragma unroll
        for (int kt = 0; kt < 16; kt += 2) {
            half8 a0 = *(const half8*)(bufA + kt * 1024 + (lane << 4));
            sacc0 = __builtin_amdgcn_mfma_f32_32x32x16_f16(a0, bq[kt], sacc0, 0, 0, 0);
            half8 a1 = *(const half8*)(bufA + (kt + 1) * 1024 + (lane << 4));
            sacc1 = __builtin_amdgcn_mfma_f32_32x32x16_f16(a1, bq[kt + 1], sacc1, 0, 0, 0);
        }
        __builtin_amdgcn_s_setprio(0);
        // masked exp from bitmask; |s|<1 so no max tracking
        const unsigned s0 = 8 * (t & 7) + h;
        unsigned x0 = (unsigned)(cw0 >> s0), x1 = (unsigned)(cw1 >> s0);
        unsigned x2 = (unsigned)(cw2 >> s0), x3 = (unsigned)(cw3 >> s0);
        float wv[16];
#pragma unroll
        for (int r = 0; r < 16; ++r) {
            unsigned xq = (r & 3) == 0 ? x0 : (r & 3) == 1 ? x1 : (r & 3) == 2 ? x2 : x3;
            float e = ((xq >> (2 * (r >> 2))) & 1u) ? __expf(sacc0[r] + sacc1[r]) : 0.f;
            wv[r] = e;
            rden += e;
        }
        // pack W -> f16 PV A-frags (validated formulas)
        int pq[8], qq[8];
#pragma unroll
        for (int q = 0; q < 8; ++q) {
            fp16x2 pp = __builtin_amdgcn_cvt_pkrtz(wv[2 * q], wv[2 * q + 1]);
            pq[q] = __builtin_bit_cast(int, pp);
            qq[q] = __shfl_xor(pq[q], 32, 64);
        }
        i32x4 af0 = {h ? qq[2] : pq[0], h ? qq[3] : pq[1], h ? pq[2] : qq[0], h ? pq[3] : qq[1]};
        i32x4 af1 = {h ? qq[6] : pq[4], h ? qq[7] : pq[5], h ? pq[6] : qq[4], h ? pq[7] : qq[5]};
        half8 afA = __builtin_bit_cast(half8, af0);
        half8 afB = __builtin_bit_cast(half8, af1);

        // PV: O[i][d] += W[i][j] * V[j][d]; B-frags DIRECT from L2 (xjF slice)
        const char* fb = gF + (size_t)(j0blk + t) * 16384 + (lane << 4);
        __builtin_amdgcn_s_setprio(1);
#pragma unroll
        for (int f = 0; f < 8; ++f) {
            half8 b0 = *(const half8*)(fb + (f * 2 + 0) * 1024);
            acc[f] = __builtin_amdgcn_mfma_f32_32x32x16_f16(afA, b0, acc[f], 0, 0, 0);
            half8 b1 = *(const half8*)(fb + (f * 2 + 1) * 1024);
            acc[f] = __builtin_amdgcn_mfma_f32_32x32x16_f16(afB, b1, acc[f], 0, 0, 0);
        }
        __builtin_amdgcn_s_setprio(0);
        if ((t & 7) == 7) { cw0 = nw0; cw1 = nw1; cw2 = nw2; cw3 = nw3; }
    }

    // den partial: plain store (block owns rows ibase..ibase+255 of slice)
    rden += __shfl_xor(rden, 32, 64);
    if (lane < 32) denp[(size_t)jsplit * N_ROWS + ibase + w * 32 + lane] = rden;

    // output partial: plain coalesced stores to private slice
    float* prow = part + (size_t)jsplit * ((size_t)N_ROWS * DDIM);
#pragma unroll
    for (int f = 0; f < 8; ++f) {
#pragma unroll
        for (int r = 0; r < 16; ++r) {
            int ir = (r & 3) + 8 * (r >> 2) + 4 * h;
            prow[(size_t)(ibase + w * 32 + ir) * DDIM + f * 32 + il] = acc[f][r];
        }
    }
#undef STAGE
}

// ---- reduce: out[i][d] = sum_s part[s][i][d] / sum_s denp[s][i] ------------
__global__ void reduce_out(const float* __restrict__ part, const float* __restrict__ denp,
                           float* __restrict__ out) {
    const int row = blockIdx.x;
    const int d   = threadIdx.x;
    float s = 0.f;
#pragma unroll
    for (int q = 0; q < 8; ++q)
        s += part[((size_t)q * N_ROWS + row) * DDIM + d];
    float dn = 0.f;
#pragma unroll
    for (int q = 0; q < 8; ++q)
        dn += denp[(size_t)q * N_ROWS + row];
    out[(size_t)row * DDIM + d] = s / dn;
}

extern "C" void kernel_launch(void* const* d_in, const int* in_sizes, int n_in,
                              void* d_out, int out_size, void* d_ws, size_t ws_size,
                              hipStream_t stream) {
    const float* xi   = (const float*)d_in[0];
    const float* xj   = (const float*)d_in[1];
    const int*   adj  = (const int*)d_in[2];
    const float* beta = (const float*)d_in[3];
    float* out = (float*)d_out;
    char*  ws  = (char*)d_ws;

    _Float16* xi_s  = (_Float16*)(ws);                // 4MB
    half8*    xjA   = (half8*)(ws + (4u << 20));      // 4MB
    half8*    xjF   = (half8*)(ws + (8u << 20));      // 4MB
    float*    denp  = (float*)(ws + (12u << 20));     // 8 x 32KB = 256KB
    u64*      maskW = (u64*)(ws + (13u << 20));       // 8MB
    float*    part  = (float*)(ws + (24u << 20));     // 8 x 8MB = 64MB

    hipFuncSetAttribute((const void*)attn_main,
                        hipFuncAttributeMaxDynamicSharedMemorySize, 65536);

    prep_scale<<<N_ROWS / 4, 256, 0, stream>>>(xi, xi_s, beta);
    prep_xj<<<M_ROWS / 32, 256, 0, stream>>>(xj, xjA, xjF);
    prep_mask<<<N_ROWS * 4 / 4, 256, 0, stream>>>(adj, maskW);
    attn_main<<<256, 512, 65536, stream>>>(xi_s, xjA, xjF, maskW, part, denp);
    reduce_out<<<N_ROWS, 256, 0, stream>>>(part, denp, out);
}

// Round 11
// 178.304 us; speedup vs baseline: 1.4655x; 1.4655x over previous
//
#include <hip/hip_runtime.h>
#include <hip/hip_bf16.h>

// ---------------------------------------------------------------------------
// CosineGraphAttentionLayer: O = softmax(beta*cos(xi,xj) + mask(adj)) @ xj
// N=M=8192, D=256, f32 in/out.
//
// R11 = R10's reuse=2 structure (4 waves x 64i as two 32-i subtiles; each
// staged frag feeds 2 MFMAs; per-CU LDS traffic halved) with SPILL-IMMUNE
// synchronization: vmcnt(0) drain before the single per-iter barrier
// (over-drain is always correct even if the compiler spills to scratch,
// which increments vmcnt and broke R10's counted vmcnt(8)), and a 2-buffer
// pipeline (stage t+1 into the buffer last read at t-1). Numerics/mask/pack/
// epilogue verbatim from validated R8/R10.
// ---------------------------------------------------------------------------

typedef _Float16 half8  __attribute__((ext_vector_type(8)));
typedef _Float16 half4v __attribute__((ext_vector_type(4)));
typedef __fp16   fp16x2 __attribute__((ext_vector_type(2)));
typedef float    f32x16 __attribute__((ext_vector_type(16)));
typedef int      i32x4  __attribute__((ext_vector_type(4)));
typedef unsigned long long u64;

#define GAS __attribute__((address_space(1)))
#define LAS __attribute__((address_space(3)))

#define N_ROWS 8192
#define M_ROWS 8192
#define DDIM   256

// ---- prep: xi * beta/||xi|| -> f16 (validated) -----------------------------
__global__ void prep_scale(const float* __restrict__ x, _Float16* __restrict__ xs,
                           const float* __restrict__ betap) {
    int row  = blockIdx.x * 4 + (threadIdx.x >> 6);
    int lane = threadIdx.x & 63;
    const float4 v = *(const float4*)(x + (size_t)row * DDIM + lane * 4);
    float ss = v.x * v.x + v.y * v.y + v.z * v.z + v.w * v.w;
#pragma unroll
    for (int o = 32; o > 0; o >>= 1) ss += __shfl_xor(ss, o, 64);
    float sc = betap[0] / sqrtf(ss);
    half4v hv = {(_Float16)(v.x * sc), (_Float16)(v.y * sc),
                 (_Float16)(v.z * sc), (_Float16)(v.w * sc)};
    *(half4v*)(xs + (size_t)row * DDIM + lane * 4) = hv;
}

// ---- prep: xj -> frag-major xjA (normalized) / xjF (raw) (validated) -------
__global__ void prep_xj(const float* __restrict__ xj, half8* __restrict__ xjA,
                        half8* __restrict__ xjF) {
    __shared__ _Float16 tileR[32][272];
    __shared__ _Float16 tileN[32][272];
    __shared__ float red[32][8];
    __shared__ float rsc[32];
    const int t  = threadIdx.x;
    const int jb = blockIdx.x;
    const int row = t >> 3, seg = t & 7;
    const float* src = xj + (size_t)(jb * 32 + row) * DDIM + seg * 32;
    float4 v[8];
    float ss = 0.f;
#pragma unroll
    for (int q = 0; q < 8; ++q) {
        v[q] = ((const float4*)src)[q];
        ss += v[q].x * v[q].x + v[q].y * v[q].y + v[q].z * v[q].z + v[q].w * v[q].w;
    }
    red[row][seg] = ss;
    __syncthreads();
    if (t < 32) {
        float s = 0.f;
#pragma unroll
        for (int q = 0; q < 8; ++q) s += red[t][q];
        rsc[t] = 1.0f / sqrtf(s);
    }
    __syncthreads();
    const float sc = rsc[row];
#pragma unroll
    for (int q = 0; q < 8; ++q) {
        int c = seg * 32 + q * 4;
        tileR[row][c + 0] = (_Float16)v[q].x;
        tileR[row][c + 1] = (_Float16)v[q].y;
        tileR[row][c + 2] = (_Float16)v[q].z;
        tileR[row][c + 3] = (_Float16)v[q].w;
        tileN[row][c + 0] = (_Float16)(v[q].x * sc);
        tileN[row][c + 1] = (_Float16)(v[q].y * sc);
        tileN[row][c + 2] = (_Float16)(v[q].z * sc);
        tileN[row][c + 3] = (_Float16)(v[q].w * sc);
    }
    __syncthreads();
#pragma unroll
    for (int rep = 0; rep < 4; ++rep) {
        int idx = t + rep * 256;
        int kt = idx >> 6, l = idx & 63, il = l & 31, hh = l >> 5;
        half8 val = *(const half8*)&tileN[il][kt * 16 + hh * 8];
        xjA[((size_t)jb * 16 + kt) * 64 + l] = val;
    }
#pragma unroll
    for (int rep = 0; rep < 4; ++rep) {
        int idx = t + rep * 256;
        int f = idx >> 7, s = (idx >> 6) & 1, l = idx & 63, il = l & 31, hh = l >> 5;
        int d = f * 32 + il, jl = s * 16 + hh * 8;
        half8 val;
#pragma unroll
        for (int e = 0; e < 8; ++e) val[e] = tileR[jl + e][d];
        xjF[((size_t)jb * 16 + f * 2 + s) * 64 + l] = val;
    }
}

// ---- prep: adj -> ballot-packed bitmask (validated R6) ---------------------
// maskW[row*128 + jq*32 + k*4 + q] bit L = (adj[row][jq*2048 + k*256 + 4L + q] != 0)
__global__ void prep_mask(const int* __restrict__ adj, u64* __restrict__ maskW) {
    const int w    = threadIdx.x >> 6;
    const int lane = threadIdx.x & 63;
    const int task = blockIdx.x * 4 + w;
    const int row  = task >> 2;
    const int jq   = task & 3;
    const int* base = adj + (size_t)row * M_ROWS + jq * 2048 + lane * 4;
    i32x4 a[8];
#pragma unroll
    for (int k = 0; k < 8; ++k)
        a[k] = __builtin_nontemporal_load((const i32x4*)(base + k * 256));
    u64 myw = 0;
#pragma unroll
    for (int k = 0; k < 8; ++k) {
        u64 b0 = __ballot(a[k][0] != 0);
        u64 b1 = __ballot(a[k][1] != 0);
        u64 b2 = __ballot(a[k][2] != 0);
        u64 b3 = __ballot(a[k][3] != 0);
        if ((lane >> 2) == k) {
            int q = lane & 3;
            myw = (q == 0) ? b0 : (q == 1) ? b1 : (q == 2) ? b2 : b3;
        }
    }
    if (lane < 32)
        maskW[(size_t)row * 128 + jq * 32 + lane] = myw;
}

// ---- main fused kernel -----------------------------------------------------
// 256 blocks x 256 threads (4 waves, 1/SIMD). jsplit = bid&7 (1024-j eighth,
// == XCD id), itile = bid>>3 (256-i tile). Wave w owns i rows [w*64, w*64+64)
// as two 32-i subtiles (A: +0, B: +32), all 256 d.
// 32 iters of 32-j tiles; tile = A(16KB)+F(16KB) staged into 2 buffers via
// global_load_lds (8 x 1KB per wave). Per iter: vmcnt(0) drain + s_barrier
// (spill-immune), then STAGE(t+1) into buf (t+1)&1, then compute buf (t&1).
// Each A-frag/V-frag read feeds 2 MFMAs (subtiles A,B) -> LDS traffic /2.
__global__ __launch_bounds__(256, 1)
void attn_main(const _Float16* __restrict__ xi_s, const half8* __restrict__ xjA,
               const half8* __restrict__ xjF, const u64* __restrict__ maskW,
               float* __restrict__ part, float* __restrict__ denp) {
    extern __shared__ char lds[];
    const int tid  = threadIdx.x;
    const int w    = tid >> 6;
    const int lane = tid & 63;
    const int il   = lane & 31;
    const int h    = lane >> 5;

    const int bid    = blockIdx.x;
    const int jsplit = bid & 7;
    const int itile  = bid >> 3;
    const int ibase  = itile * 256;
    const int irowA  = ibase + w * 64 + il;
    const int irowB  = irowA + 32;
    const int j0blk  = jsplit * 32;         // first 32-j block of our eighth

    half8 bq0[16], bq1[16];
#pragma unroll
    for (int kt = 0; kt < 16; ++kt) {
        bq0[kt] = *(const half8*)(xi_s + (size_t)irowA * DDIM + kt * 16 + h * 8);
        bq1[kt] = *(const half8*)(xi_s + (size_t)irowB * DDIM + kt * 16 + h * 8);
    }

    f32x16 accA[8], accB[8];
#pragma unroll
    for (int f = 0; f < 8; ++f)
#pragma unroll
        for (int r = 0; r < 16; ++r) { accA[f][r] = 0.f; accB[f][r] = 0.f; }
    float rdenA = 0.f, rdenB = 0.f;

    const u64* mrowA = maskW + (size_t)irowA * 128 + (jsplit >> 1) * 32;
    const u64* mrowB = maskW + (size_t)irowB * 128 + (jsplit >> 1) * 32;
    const int  kbase = (jsplit & 1) * 4;    // chunk base within quarter
    const char* gA = (const char*)xjA;
    const char* gF = (const char*)xjF;

    // STAGE tile T (32KB: A 16K | F 16K) into buffer B; each wave stages a
    // contiguous 8KB chunk (waves 0,1 -> A; waves 2,3 -> F), 8 x 1KB loads.
#define STAGE(T, B)                                                             \
    {                                                                           \
        const size_t blk = (size_t)(j0blk + (T)) * 16384;                       \
        const char* src = (w < 2 ? gA : gF) + blk + (w & 1) * 8192 + (lane << 4); \
        char* dst = lds + (B) * 32768 + (w < 2 ? 0 : 16384) + (w & 1) * 8192 + (lane << 4); \
        _Pragma("unroll")                                                       \
        for (int k = 0; k < 8; ++k)                                             \
            __builtin_amdgcn_global_load_lds(                                   \
                (const GAS unsigned int*)(src + k * 1024),                      \
                (LAS unsigned int*)(dst + k * 1024), 16, 0, 0);                 \
    }

    STAGE(0, 0);
    u64 cwA0, cwA1, cwA2, cwA3, cwB0, cwB1, cwB2, cwB3;

    for (int t = 0; t < 32; ++t) {
        // drain ALL outstanding VMEM (stage t + any compiler scratch/mask ops
        // — over-drain is always correct), then sync the workgroup.
        asm volatile("s_waitcnt vmcnt(0)" ::: "memory");
        __builtin_amdgcn_s_barrier();
        __builtin_amdgcn_sched_barrier(0);

        // mask words for this 8-iter group
        if ((t & 7) == 0) {
            int k = kbase + (t >> 3);
            cwA0 = mrowA[k * 4 + 0]; cwA1 = mrowA[k * 4 + 1];
            cwA2 = mrowA[k * 4 + 2]; cwA3 = mrowA[k * 4 + 3];
            cwB0 = mrowB[k * 4 + 0]; cwB1 = mrowB[k * 4 + 1];
            cwB2 = mrowB[k * 4 + 2]; cwB3 = mrowB[k * 4 + 3];
        }
        // stage next tile into the buffer last read at iter t-1 (all waves
        // are past the barrier, so no one still reads it)
        if (t < 31) STAGE(t + 1, (t + 1) & 1);

        const char* bufA = lds + (t & 1) * 32768;
        const char* bufF = bufA + 16384;

        // QK^T: S^T[j][i] for both i-subtiles; each A-frag feeds 2 MFMAs
        f32x16 sacc0, sacc1;
#pragma unroll
        for (int r = 0; r < 16; ++r) { sacc0[r] = 0.f; sacc1[r] = 0.f; }
#pragma unroll
        for (int kt = 0; kt < 16; ++kt) {
            half8 afr = *(const half8*)(bufA + kt * 1024 + (lane << 4));
            sacc0 = __builtin_amdgcn_mfma_f32_32x32x16_f16(afr, bq0[kt], sacc0, 0, 0, 0);
            sacc1 = __builtin_amdgcn_mfma_f32_32x32x16_f16(afr, bq1[kt], sacc1, 0, 0, 0);
        }
        // masked exp + pack, subtile A then B (validated formulas)
        const unsigned s0 = 8 * (t & 7) + h;
        half8 afA0, afB0, afA1, afB1;
        {
            unsigned x0 = (unsigned)(cwA0 >> s0), x1 = (unsigned)(cwA1 >> s0);
            unsigned x2 = (unsigned)(cwA2 >> s0), x3 = (unsigned)(cwA3 >> s0);
            float wv[16];
#pragma unroll
            for (int r = 0; r < 16; ++r) {
                unsigned xq = (r & 3) == 0 ? x0 : (r & 3) == 1 ? x1 : (r & 3) == 2 ? x2 : x3;
                float e = ((xq >> (2 * (r >> 2))) & 1u) ? __expf(sacc0[r]) : 0.f;
                wv[r] = e;
                rdenA += e;
            }
            int pq[8], qq[8];
#pragma unroll
            for (int q = 0; q < 8; ++q) {
                fp16x2 pp = __builtin_amdgcn_cvt_pkrtz(wv[2 * q], wv[2 * q + 1]);
                pq[q] = __builtin_bit_cast(int, pp);
                qq[q] = __shfl_xor(pq[q], 32, 64);
            }
            i32x4 f0 = {h ? qq[2] : pq[0], h ? qq[3] : pq[1], h ? pq[2] : qq[0], h ? pq[3] : qq[1]};
            i32x4 f1 = {h ? qq[6] : pq[4], h ? qq[7] : pq[5], h ? pq[6] : qq[4], h ? pq[7] : qq[5]};
            afA0 = __builtin_bit_cast(half8, f0);
            afB0 = __builtin_bit_cast(half8, f1);
        }
        {
            unsigned x0 = (unsigned)(cwB0 >> s0), x1 = (unsigned)(cwB1 >> s0);
            unsigned x2 = (unsigned)(cwB2 >> s0), x3 = (unsigned)(cwB3 >> s0);
            float wv[16];
#pragma unroll
            for (int r = 0; r < 16; ++r) {
                unsigned xq = (r & 3) == 0 ? x0 : (r & 3) == 1 ? x1 : (r & 3) == 2 ? x2 : x3;
                float e = ((xq >> (2 * (r >> 2))) & 1u) ? __expf(sacc1[r]) : 0.f;
                wv[r] = e;
                rdenB += e;
            }
            int pq[8], qq[8];
#pragma unroll
            for (int q = 0; q < 8; ++q) {
                fp16x2 pp = __builtin_amdgcn_cvt_pkrtz(wv[2 * q], wv[2 * q + 1]);
                pq[q] = __builtin_bit_cast(int, pp);
                qq[q] = __shfl_xor(pq[q], 32, 64);
            }
            i32x4 f0 = {h ? qq[2] : pq[0], h ? qq[3] : pq[1], h ? pq[2] : qq[0], h ? pq[3] : qq[1]};
            i32x4 f1 = {h ? qq[6] : pq[4], h ? qq[7] : pq[5], h ? pq[6] : qq[4], h ? pq[7] : qq[5]};
            afA1 = __builtin_bit_cast(half8, f0);
            afB1 = __builtin_bit_cast(half8, f1);
        }

        // PV: each V-frag read feeds 2 MFMAs (accA, accB)
#pragma unroll
        for (int f = 0; f < 8; ++f) {
            half8 b0 = *(const half8*)(bufF + (f * 2 + 0) * 1024 + (lane << 4));
            accA[f] = __builtin_amdgcn_mfma_f32_32x32x16_f16(afA0, b0, accA[f], 0, 0, 0);
            accB[f] = __builtin_amdgcn_mfma_f32_32x32x16_f16(afA1, b0, accB[f], 0, 0, 0);
            half8 b1 = *(const half8*)(bufF + (f * 2 + 1) * 1024 + (lane << 4));
            accA[f] = __builtin_amdgcn_mfma_f32_32x32x16_f16(afB0, b1, accA[f], 0, 0, 0);
            accB[f] = __builtin_amdgcn_mfma_f32_32x32x16_f16(afB1, b1, accB[f], 0, 0, 0);
        }
    }

    // den partials: plain stores
    rdenA += __shfl_xor(rdenA, 32, 64);
    rdenB += __shfl_xor(rdenB, 32, 64);
    if (lane < 32) {
        denp[(size_t)jsplit * N_ROWS + ibase + w * 64 + lane] = rdenA;
        denp[(size_t)jsplit * N_ROWS + ibase + w * 64 + 32 + lane] = rdenB;
    }

    // output partials: plain coalesced stores to private slice
    float* prow = part + (size_t)jsplit * ((size_t)N_ROWS * DDIM);
#pragma unroll
    for (int f = 0; f < 8; ++f) {
#pragma unroll
        for (int r = 0; r < 16; ++r) {
            int ir = (r & 3) + 8 * (r >> 2) + 4 * h;
            prow[(size_t)(ibase + w * 64 + ir) * DDIM + f * 32 + il] = accA[f][r];
            prow[(size_t)(ibase + w * 64 + 32 + ir) * DDIM + f * 32 + il] = accB[f][r];
        }
    }
#undef STAGE
}

// ---- reduce: out[i][d] = sum_s part[s][i][d] / sum_s denp[s][i] ------------
__global__ void reduce_out(const float* __restrict__ part, const float* __restrict__ denp,
                           float* __restrict__ out) {
    const int row = blockIdx.x;
    const int d   = threadIdx.x;
    float s = 0.f;
#pragma unroll
    for (int q = 0; q < 8; ++q)
        s += part[((size_t)q * N_ROWS + row) * DDIM + d];
    float dn = 0.f;
#pragma unroll
    for (int q = 0; q < 8; ++q)
        dn += denp[(size_t)q * N_ROWS + row];
    out[(size_t)row * DDIM + d] = s / dn;
}

extern "C" void kernel_launch(void* const* d_in, const int* in_sizes, int n_in,
                              void* d_out, int out_size, void* d_ws, size_t ws_size,
                              hipStream_t stream) {
    const float* xi   = (const float*)d_in[0];
    const float* xj   = (const float*)d_in[1];
    const int*   adj  = (const int*)d_in[2];
    const float* beta = (const float*)d_in[3];
    float* out = (float*)d_out;
    char*  ws  = (char*)d_ws;

    _Float16* xi_s  = (_Float16*)(ws);                // 4MB
    half8*    xjA   = (half8*)(ws + (4u << 20));      // 4MB
    half8*    xjF   = (half8*)(ws + (8u << 20));      // 4MB
    float*    denp  = (float*)(ws + (12u << 20));     // 8 x 32KB = 256KB
    u64*      maskW = (u64*)(ws + (13u << 20));       // 8MB
    float*    part  = (float*)(ws + (24u << 20));     // 8 x 8MB = 64MB

    hipFuncSetAttribute((const void*)attn_main,
                        hipFuncAttributeMaxDynamicSharedMemorySize, 65536);

    prep_scale<<<N_ROWS / 4, 256, 0, stream>>>(xi, xi_s, beta);
    prep_xj<<<M_ROWS / 32, 256, 0, stream>>>(xj, xjA, xjF);
    prep_mask<<<N_ROWS * 4 / 4, 256, 0, stream>>>(adj, maskW);
    attn_main<<<256, 256, 65536, stream>>>(xi_s, xjA, xjF, maskW, part, denp);
    reduce_out<<<N_ROWS, 256, 0, stream>>>(part, denp, out);
}

// Round 12
// 154.297 us; speedup vs baseline: 1.6935x; 1.1556x over previous
//
#include <hip/hip_runtime.h>
#include <hip/hip_bf16.h>

// ---------------------------------------------------------------------------
// CosineGraphAttentionLayer: O = softmax(beta*cos(xi,xj) + mask(adj)) @ xj
// N=M=8192, D=256, f32 in/out.
//
// R12 = R8 numerics/dataflow with the barrier-convoy fixed: BM=128, 4 waves,
// 512 blocks (2 independent blocks/CU -> one block computes while the other
// drains/barriers). Double-buffered 32KB tiles (A 16K | F 16K) staged via
// global_load_lds; spill-immune vmcnt(0)+s_barrier per iter (128 VGPR, no
// spill). Mask bitmask, pack formulas, partial-store epilogue, preps, reduce
// verbatim from validated R8.
// ---------------------------------------------------------------------------

typedef _Float16 half8  __attribute__((ext_vector_type(8)));
typedef _Float16 half4v __attribute__((ext_vector_type(4)));
typedef __fp16   fp16x2 __attribute__((ext_vector_type(2)));
typedef float    f32x16 __attribute__((ext_vector_type(16)));
typedef int      i32x4  __attribute__((ext_vector_type(4)));
typedef unsigned long long u64;

#define GAS __attribute__((address_space(1)))
#define LAS __attribute__((address_space(3)))

#define N_ROWS 8192
#define M_ROWS 8192
#define DDIM   256

// ---- prep: xi * beta/||xi|| -> f16 (validated) -----------------------------
__global__ void prep_scale(const float* __restrict__ x, _Float16* __restrict__ xs,
                           const float* __restrict__ betap) {
    int row  = blockIdx.x * 4 + (threadIdx.x >> 6);
    int lane = threadIdx.x & 63;
    const float4 v = *(const float4*)(x + (size_t)row * DDIM + lane * 4);
    float ss = v.x * v.x + v.y * v.y + v.z * v.z + v.w * v.w;
#pragma unroll
    for (int o = 32; o > 0; o >>= 1) ss += __shfl_xor(ss, o, 64);
    float sc = betap[0] / sqrtf(ss);
    half4v hv = {(_Float16)(v.x * sc), (_Float16)(v.y * sc),
                 (_Float16)(v.z * sc), (_Float16)(v.w * sc)};
    *(half4v*)(xs + (size_t)row * DDIM + lane * 4) = hv;
}

// ---- prep: xj -> frag-major xjA (normalized) / xjF (raw) (validated) -------
__global__ void prep_xj(const float* __restrict__ xj, half8* __restrict__ xjA,
                        half8* __restrict__ xjF) {
    __shared__ _Float16 tileR[32][272];
    __shared__ _Float16 tileN[32][272];
    __shared__ float red[32][8];
    __shared__ float rsc[32];
    const int t  = threadIdx.x;
    const int jb = blockIdx.x;
    const int row = t >> 3, seg = t & 7;
    const float* src = xj + (size_t)(jb * 32 + row) * DDIM + seg * 32;
    float4 v[8];
    float ss = 0.f;
#pragma unroll
    for (int q = 0; q < 8; ++q) {
        v[q] = ((const float4*)src)[q];
        ss += v[q].x * v[q].x + v[q].y * v[q].y + v[q].z * v[q].z + v[q].w * v[q].w;
    }
    red[row][seg] = ss;
    __syncthreads();
    if (t < 32) {
        float s = 0.f;
#pragma unroll
        for (int q = 0; q < 8; ++q) s += red[t][q];
        rsc[t] = 1.0f / sqrtf(s);
    }
    __syncthreads();
    const float sc = rsc[row];
#pragma unroll
    for (int q = 0; q < 8; ++q) {
        int c = seg * 32 + q * 4;
        tileR[row][c + 0] = (_Float16)v[q].x;
        tileR[row][c + 1] = (_Float16)v[q].y;
        tileR[row][c + 2] = (_Float16)v[q].z;
        tileR[row][c + 3] = (_Float16)v[q].w;
        tileN[row][c + 0] = (_Float16)(v[q].x * sc);
        tileN[row][c + 1] = (_Float16)(v[q].y * sc);
        tileN[row][c + 2] = (_Float16)(v[q].z * sc);
        tileN[row][c + 3] = (_Float16)(v[q].w * sc);
    }
    __syncthreads();
#pragma unroll
    for (int rep = 0; rep < 4; ++rep) {
        int idx = t + rep * 256;
        int kt = idx >> 6, l = idx & 63, il = l & 31, hh = l >> 5;
        half8 val = *(const half8*)&tileN[il][kt * 16 + hh * 8];
        xjA[((size_t)jb * 16 + kt) * 64 + l] = val;
    }
#pragma unroll
    for (int rep = 0; rep < 4; ++rep) {
        int idx = t + rep * 256;
        int f = idx >> 7, s = (idx >> 6) & 1, l = idx & 63, il = l & 31, hh = l >> 5;
        int d = f * 32 + il, jl = s * 16 + hh * 8;
        half8 val;
#pragma unroll
        for (int e = 0; e < 8; ++e) val[e] = tileR[jl + e][d];
        xjF[((size_t)jb * 16 + f * 2 + s) * 64 + l] = val;
    }
}

// ---- prep: adj -> ballot-packed bitmask (validated R6) ---------------------
// maskW[row*128 + jq*32 + k*4 + q] bit L = (adj[row][jq*2048 + k*256 + 4L + q] != 0)
__global__ void prep_mask(const int* __restrict__ adj, u64* __restrict__ maskW) {
    const int w    = threadIdx.x >> 6;
    const int lane = threadIdx.x & 63;
    const int task = blockIdx.x * 4 + w;
    const int row  = task >> 2;
    const int jq   = task & 3;
    const int* base = adj + (size_t)row * M_ROWS + jq * 2048 + lane * 4;
    i32x4 a[8];
#pragma unroll
    for (int k = 0; k < 8; ++k)
        a[k] = __builtin_nontemporal_load((const i32x4*)(base + k * 256));
    u64 myw = 0;
#pragma unroll
    for (int k = 0; k < 8; ++k) {
        u64 b0 = __ballot(a[k][0] != 0);
        u64 b1 = __ballot(a[k][1] != 0);
        u64 b2 = __ballot(a[k][2] != 0);
        u64 b3 = __ballot(a[k][3] != 0);
        if ((lane >> 2) == k) {
            int q = lane & 3;
            myw = (q == 0) ? b0 : (q == 1) ? b1 : (q == 2) ? b2 : b3;
        }
    }
    if (lane < 32)
        maskW[(size_t)row * 128 + jq * 32 + lane] = myw;
}

// ---- main fused kernel -----------------------------------------------------
// 512 blocks x 256 threads (4 waves; 2 blocks/CU). jsplit = bid&7 (1024-j
// eighth, == XCD id), itile = bid>>3 (128-i tile). Wave w owns i-subtile w
// (32 i), all 256 d. 32 iters of 32-j tiles; tile = A(16KB)+F(16KB) staged
// into 2 buffers via global_load_lds (8 x 1KB per wave). Per iter: vmcnt(0)
// drain + s_barrier (spill-immune; cross-block TLP hides the drain), then
// STAGE(t+1) into buf (t+1)&1, then compute buf t&1.
__global__ __launch_bounds__(256, 2)
void attn_main(const _Float16* __restrict__ xi_s, const half8* __restrict__ xjA,
               const half8* __restrict__ xjF, const u64* __restrict__ maskW,
               float* __restrict__ part, float* __restrict__ denp) {
    extern __shared__ char lds[];
    const int tid  = threadIdx.x;
    const int w    = tid >> 6;
    const int lane = tid & 63;
    const int il   = lane & 31;
    const int h    = lane >> 5;

    const int bid    = blockIdx.x;
    const int jsplit = bid & 7;
    const int itile  = bid >> 3;
    const int ibase  = itile * 128;
    const int irow   = ibase + w * 32 + il;
    const int j0blk  = jsplit * 32;         // first 32-j block of our eighth

    half8 bq[16];
#pragma unroll
    for (int kt = 0; kt < 16; ++kt)
        bq[kt] = *(const half8*)(xi_s + (size_t)irow * DDIM + kt * 16 + h * 8);

    f32x16 acc[8];
#pragma unroll
    for (int f = 0; f < 8; ++f)
#pragma unroll
        for (int r = 0; r < 16; ++r) acc[f][r] = 0.f;
    float rden = 0.f;

    const u64* mrow = maskW + (size_t)irow * 128 + (jsplit >> 1) * 32;
    const int  kbase = (jsplit & 1) * 4;    // chunk base within quarter
    const char* gA = (const char*)xjA;
    const char* gF = (const char*)xjF;

    // STAGE tile T (32KB: A 16K | F 16K) into buffer B; each wave stages a
    // contiguous 8KB chunk (waves 0,1 -> A; waves 2,3 -> F), 8 x 1KB loads.
#define STAGE(T, B)                                                             \
    {                                                                           \
        const size_t blk = (size_t)(j0blk + (T)) * 16384;                       \
        const char* src = (w < 2 ? gA : gF) + blk + (w & 1) * 8192 + (lane << 4); \
        char* dst = lds + (B) * 32768 + (w < 2 ? 0 : 16384) + (w & 1) * 8192 + (lane << 4); \
        _Pragma("unroll")                                                       \
        for (int k = 0; k < 8; ++k)                                             \
            __builtin_amdgcn_global_load_lds(                                   \
                (const GAS unsigned int*)(src + k * 1024),                      \
                (LAS unsigned int*)(dst + k * 1024), 16, 0, 0);                 \
    }

    STAGE(0, 0);
    u64 cw0, cw1, cw2, cw3;

    for (int t = 0; t < 32; ++t) {
        // drain ALL outstanding VMEM (stage t + any other loads — over-drain
        // is always correct), then sync the workgroup.
        asm volatile("s_waitcnt vmcnt(0)" ::: "memory");
        __builtin_amdgcn_s_barrier();
        __builtin_amdgcn_sched_barrier(0);

        // mask words for this 8-iter group
        if ((t & 7) == 0) {
            int k = kbase + (t >> 3);
            cw0 = mrow[k * 4 + 0]; cw1 = mrow[k * 4 + 1];
            cw2 = mrow[k * 4 + 2]; cw3 = mrow[k * 4 + 3];
        }
        // stage next tile into the buffer last read at iter t-1 (all waves
        // are past the barrier, so none still reads it)
        if (t < 31) STAGE(t + 1, (t + 1) & 1);

        const char* bufA = lds + (t & 1) * 32768;
        const char* bufF = bufA + 16384;

        // QK^T: S^T[j][i], 32j x 32i — two interleaved chains for MFMA ILP
        f32x16 sacc0, sacc1;
#pragma unroll
        for (int r = 0; r < 16; ++r) { sacc0[r] = 0.f; sacc1[r] = 0.f; }
#pragma unroll
        for (int kt = 0; kt < 16; kt += 2) {
            half8 a0 = *(const half8*)(bufA + kt * 1024 + (lane << 4));
            sacc0 = __builtin_amdgcn_mfma_f32_32x32x16_f16(a0, bq[kt], sacc0, 0, 0, 0);
            half8 a1 = *(const half8*)(bufA + (kt + 1) * 1024 + (lane << 4));
            sacc1 = __builtin_amdgcn_mfma_f32_32x32x16_f16(a1, bq[kt + 1], sacc1, 0, 0, 0);
        }
        // masked exp from bitmask; |s|<1 so no max tracking
        const unsigned s0 = 8 * (t & 7) + h;
        unsigned x0 = (unsigned)(cw0 >> s0), x1 = (unsigned)(cw1 >> s0);
        unsigned x2 = (unsigned)(cw2 >> s0), x3 = (unsigned)(cw3 >> s0);
        float wv[16];
#pragma unroll
        for (int r = 0; r < 16; ++r) {
            unsigned xq = (r & 3) == 0 ? x0 : (r & 3) == 1 ? x1 : (r & 3) == 2 ? x2 : x3;
            float e = ((xq >> (2 * (r >> 2))) & 1u) ? __expf(sacc0[r] + sacc1[r]) : 0.f;
            wv[r] = e;
            rden += e;
        }
        // pack W -> f16 PV A-frags (validated formulas)
        int pq[8], qq[8];
#pragma unroll
        for (int q = 0; q < 8; ++q) {
            fp16x2 pp = __builtin_amdgcn_cvt_pkrtz(wv[2 * q], wv[2 * q + 1]);
            pq[q] = __builtin_bit_cast(int, pp);
            qq[q] = __shfl_xor(pq[q], 32, 64);
        }
        i32x4 af0 = {h ? qq[2] : pq[0], h ? qq[3] : pq[1], h ? pq[2] : qq[0], h ? pq[3] : qq[1]};
        i32x4 af1 = {h ? qq[6] : pq[4], h ? qq[7] : pq[5], h ? pq[6] : qq[4], h ? pq[7] : qq[5]};
        half8 afA = __builtin_bit_cast(half8, af0);
        half8 afB = __builtin_bit_cast(half8, af1);

        // PV: O[i][d] += W[i][j] * V[j][d], k = 32 j, all 256 d
#pragma unroll
        for (int f = 0; f < 8; ++f) {
            half8 b0 = *(const half8*)(bufF + (f * 2 + 0) * 1024 + (lane << 4));
            acc[f] = __builtin_amdgcn_mfma_f32_32x32x16_f16(afA, b0, acc[f], 0, 0, 0);
            half8 b1 = *(const half8*)(bufF + (f * 2 + 1) * 1024 + (lane << 4));
            acc[f] = __builtin_amdgcn_mfma_f32_32x32x16_f16(afB, b1, acc[f], 0, 0, 0);
        }
    }

    // den partial: plain store
    rden += __shfl_xor(rden, 32, 64);
    if (lane < 32) denp[(size_t)jsplit * N_ROWS + ibase + w * 32 + lane] = rden;

    // output partial: plain coalesced stores to private slice
    float* prow = part + (size_t)jsplit * ((size_t)N_ROWS * DDIM);
#pragma unroll
    for (int f = 0; f < 8; ++f) {
#pragma unroll
        for (int r = 0; r < 16; ++r) {
            int ir = (r & 3) + 8 * (r >> 2) + 4 * h;
            prow[(size_t)(ibase + w * 32 + ir) * DDIM + f * 32 + il] = acc[f][r];
        }
    }
#undef STAGE
}

// ---- reduce: out[i][d] = sum_s part[s][i][d] / sum_s denp[s][i] ------------
__global__ void reduce_out(const float* __restrict__ part, const float* __restrict__ denp,
                           float* __restrict__ out) {
    const int row = blockIdx.x;
    const int d   = threadIdx.x;
    float s = 0.f;
#pragma unroll
    for (int q = 0; q < 8; ++q)
        s += part[((size_t)q * N_ROWS + row) * DDIM + d];
    float dn = 0.f;
#pragma unroll
    for (int q = 0; q < 8; ++q)
        dn += denp[(size_t)q * N_ROWS + row];
    out[(size_t)row * DDIM + d] = s / dn;
}

extern "C" void kernel_launch(void* const* d_in, const int* in_sizes, int n_in,
                              void* d_out, int out_size, void* d_ws, size_t ws_size,
                              hipStream_t stream) {
    const float* xi   = (const float*)d_in[0];
    const float* xj   = (const float*)d_in[1];
    const int*   adj  = (const int*)d_in[2];
    const float* beta = (const float*)d_in[3];
    float* out = (float*)d_out;
    char*  ws  = (char*)d_ws;

    _Float16* xi_s  = (_Float16*)(ws);                // 4MB
    half8*    xjA   = (half8*)(ws + (4u << 20));      // 4MB
    half8*    xjF   = (half8*)(ws + (8u << 20));      // 4MB
    float*    denp  = (float*)(ws + (12u << 20));     // 8 x 32KB = 256KB
    u64*      maskW = (u64*)(ws + (13u << 20));       // 8MB
    float*    part  = (float*)(ws + (24u << 20));     // 8 x 8MB = 64MB

    hipFuncSetAttribute((const void*)attn_main,
                        hipFuncAttributeMaxDynamicSharedMemorySize, 65536);

    prep_scale<<<N_ROWS / 4, 256, 0, stream>>>(xi, xi_s, beta);
    prep_xj<<<M_ROWS / 32, 256, 0, stream>>>(xj, xjA, xjF);
    prep_mask<<<N_ROWS * 4 / 4, 256, 0, stream>>>(adj, maskW);
    attn_main<<<512, 256, 65536, stream>>>(xi_s, xjA, xjF, maskW, part, denp);
    reduce_out<<<N_ROWS, 256, 0, stream>>>(part, denp, out);
}